// Round 5
// baseline (401.471 us; speedup 1.0000x reference)
//
#include <hip/hip_runtime.h>
#include <math.h>

// ---------------------------------------------------------------------------
// HyperbolicInfoNCE on MI355X — Round 5: full-K fragment prefetch + fused
// finalize (last-block-done).
//
// R4 post-mortem: XCD swizzle regressed (128->147us). FETCH_SIZE was already
// ~11.6MB -> loads were L3-resident all along; the stall is per-wave memory-
// level parallelism (compiler keeps only one kt of fragments in flight at
// VGPR=92). Fix: load ALL 40 fragments (5 kt x 4 x A/B) before any MFMA --
// one ~600cyc latency exposure per wave instead of five, hidden by the other
// resident wave's ~3000cyc trans epilogue. Also fuse the finalize kernel into
// the GEMM via a device-scope done-counter (saves one ~15us launch gap).
// ---------------------------------------------------------------------------

#define BDIM   8192
#define K_IN   129
#define K_PAD  160      // 5 * 32
#define TILE   128
#define BK     32
#define NKT    (K_PAD / BK)   // 5
#define NTILES 4096           // (8192/128)^2

typedef __bf16  bf16x8 __attribute__((ext_vector_type(8)));
typedef float   f32x4  __attribute__((ext_vector_type(4)));

// ws layout (bytes)
#define OFF_A    0u
#define OFF_B    (BDIM * K_PAD * 2u)                  // 2,621,440
#define OFF_RS   (2u * BDIM * K_PAD * 2u)             // 5,242,880
#define OFF_CS   (OFF_RS + BDIM * 4u)
#define OFF_DG   (OFF_CS + BDIM * 4u)
#define OFF_CNT  (OFF_DG + BDIM * 4u)

// ---- hardware transcendentals (v_sqrt_f32 / v_log_f32 / v_exp_f32) ----
__device__ __forceinline__ float fast_sqrt(float x) {
#if __has_builtin(__builtin_amdgcn_sqrtf)
    return __builtin_amdgcn_sqrtf(x);
#else
    return sqrtf(x);
#endif
}
__device__ __forceinline__ float fast_log2(float x) {
#if __has_builtin(__builtin_amdgcn_logf)
    return __builtin_amdgcn_logf(x);       // log base 2
#else
    return __log2f(x);
#endif
}
__device__ __forceinline__ float fast_exp2(float x) {
#if __has_builtin(__builtin_amdgcn_exp2f)
    return __builtin_amdgcn_exp2f(x);      // 2^x
#else
    extern "C" __device__ float __ocml_native_exp2_f32(float);
    return __ocml_native_exp2_f32(x);
#endif
}

__device__ __forceinline__ unsigned short f2bf_rne(float f) {
    unsigned int u = __float_as_uint(f);
    u += 0x7FFFu + ((u >> 16) & 1u);   // round-to-nearest-even
    return (unsigned short)(u >> 16);
}

// ---------------------------------------------------------------------------
// Kernel 1: fp32 -> bf16, K zero-padded 129->160, Lorentz metric folded into
// A (negate column 0 of z1). Also zeroes row_sum/col_sum and the done-counter.
// ---------------------------------------------------------------------------
__global__ __launch_bounds__(256) void convert_kernel(
    const float* __restrict__ z1, const float* __restrict__ z2,
    unsigned short* __restrict__ A, unsigned short* __restrict__ B,
    float* __restrict__ rs_cs, unsigned int* __restrict__ cnt)
{
    int idx = blockIdx.x * 256 + threadIdx.x;
    if (idx < 2 * BDIM) rs_cs[idx] = 0.f;
    if (idx == 0) *cnt = 0u;
    if (idx >= BDIM * K_PAD) return;
    int r = idx / K_PAD;
    int c = idx - r * K_PAD;
    float va = 0.f, vb = 0.f;
    if (c < K_IN) {
        va = z1[r * K_IN + c];
        vb = z2[r * K_IN + c];
        if (c == 0) va = -va;          // Lorentz metric on first coordinate
    }
    A[idx] = f2bf_rne(va);
    B[idx] = f2bf_rne(vb);
}

// ---------------------------------------------------------------------------
// Kernel 2: 128x128-tile MFMA GEMM, ALL fragments prefetched to registers
// (no LDS staging), fused acosh/exp epilogue + row/col partial sums, and
// fused finalize in the last block to finish (device-scope counter).
//   2D grid 64x64 (R3 mapping — R4's XCD swizzle regressed).
//   block = 4 waves (2x2), wave tile 64x64, 4x4 MFMA 16x16x32
//   fragment layouts (guide-verified, m89/m91):
//     A/B: elem [m=lane&15][k=(lane>>4)*8 + j]
//     C/D: elem [row=(lane>>4)*4 + reg][col=lane&15]
// ---------------------------------------------------------------------------
__global__ __launch_bounds__(256) void gemm_epilogue_kernel(
    const unsigned short* __restrict__ A, const unsigned short* __restrict__ B,
    float* __restrict__ row_sum, float* __restrict__ col_sum,
    float* __restrict__ diag, unsigned int* __restrict__ cnt,
    float* __restrict__ out)
{
    const int t    = threadIdx.x;
    const int lane = t & 63;
    const int wave = t >> 6;
    const int quad = lane >> 4;
    const int l16  = lane & 15;
    const int wr   = (wave >> 1) * 64;   // wave row offset in tile
    const int wc   = (wave & 1) * 64;    // wave col offset in tile
    const int rowBase = blockIdx.y * TILE;
    const int colBase = blockIdx.x * TILE;

    const unsigned short* Abase = A + (rowBase + wr + l16) * K_PAD + quad * 8;
    const unsigned short* Bbase = B + (colBase + wc + l16) * K_PAD + quad * 8;

    // ---- prefetch ALL fragments: 40 independent 16B loads in flight ----
    bf16x8 af[NKT][4], bfr[NKT][4];
    #pragma unroll
    for (int kt = 0; kt < NKT; ++kt) {
        #pragma unroll
        for (int i = 0; i < 4; ++i) {
            af[kt][i]  = *(const bf16x8*)(Abase + i * 16 * K_PAD + kt * BK);
            bfr[kt][i] = *(const bf16x8*)(Bbase + i * 16 * K_PAD + kt * BK);
        }
    }

    f32x4 acc[4][4] = {};
    #pragma unroll
    for (int kt = 0; kt < NKT; ++kt)
        #pragma unroll
        for (int i = 0; i < 4; ++i)
            #pragma unroll
            for (int j = 0; j < 4; ++j)
                acc[i][j] = __builtin_amdgcn_mfma_f32_16x16x32_bf16(
                                af[kt][i], bfr[kt][j], acc[i][j], 0, 0, 0);

    // ---- fused epilogue ----
    // u = x + sqrt(x^2-1), x = max(-inner, 1+1e-6)
    // exp(sims) = u^(-1/0.07) = exp2(-14.2857142857 * log2(u))
    // sims      = -(ln2/0.07) * log2(u)
    const bool diagWave = (rowBase + wr) == (colBase + wc);
    float rowp[4][4] = {};
    float colp[4]    = {0.f, 0.f, 0.f, 0.f};

    #pragma unroll
    for (int i = 0; i < 4; ++i) {
        #pragma unroll
        for (int j = 0; j < 4; ++j) {
            #pragma unroll
            for (int reg = 0; reg < 4; ++reg) {
                float inner = acc[i][j][reg];
                float x = fmaxf(-inner, 1.000001f);
                float s = fast_sqrt(__builtin_fmaf(x, x, -1.0f));
                float l2u = fast_log2(x + s);
                float e = fast_exp2(-14.285714285714286f * l2u);
                rowp[i][reg] += e;
                colp[j]      += e;
                if (diagWave && i == j && (quad * 4 + reg) == l16) {
                    int R = rowBase + wr + i * 16 + quad * 4 + reg;
                    diag[R] = -9.902102579427789f * l2u;
                }
            }
        }
    }

    // row sums: reduce across the 16 lanes of each quad (they hold 4 cols each)
    #pragma unroll
    for (int i = 0; i < 4; ++i) {
        #pragma unroll
        for (int reg = 0; reg < 4; ++reg) {
            float v = rowp[i][reg];
            v += __shfl_xor(v, 1);
            v += __shfl_xor(v, 2);
            v += __shfl_xor(v, 4);
            v += __shfl_xor(v, 8);
            if (l16 == 0)
                atomicAdd(&row_sum[rowBase + wr + i * 16 + quad * 4 + reg], v);
        }
    }
    // col sums: reduce across quads
    #pragma unroll
    for (int j = 0; j < 4; ++j) {
        float v = colp[j];
        v += __shfl_xor(v, 16);
        v += __shfl_xor(v, 32);
        if (quad == 0)
            atomicAdd(&col_sum[colBase + wc + j * 16 + l16], v);
    }

    // ---- fused finalize: last block to finish computes the loss ----
    __shared__ unsigned int lastFlag;
    __shared__ float part[4];
    __threadfence();                       // release my stores/atomics
    __syncthreads();                       // all threads in block fenced
    if (t == 0) {
        unsigned int old = atomicAdd(cnt, 1u);   // device-scope
        lastFlag = (old == NTILES - 1u) ? 1u : 0u;
    }
    __syncthreads();
    if (lastFlag) {
        __threadfence();                   // acquire side
        const float LN2_HALF = 0.34657359027997264f;  // 0.5 * ln2
        float a = 0.f;
        for (int b = t; b < BDIM; b += 256) {
            float r = __hip_atomic_load(&row_sum[b], __ATOMIC_RELAXED,
                                        __HIP_MEMORY_SCOPE_AGENT);
            float c = __hip_atomic_load(&col_sum[b], __ATOMIC_RELAXED,
                                        __HIP_MEMORY_SCOPE_AGENT);
            float d = __hip_atomic_load(&diag[b], __ATOMIC_RELAXED,
                                        __HIP_MEMORY_SCOPE_AGENT);
            a += LN2_HALF * (fast_log2(r) + fast_log2(c)) - d;
        }
        #pragma unroll
        for (int m = 1; m < 64; m <<= 1) a += __shfl_xor(a, m);
        if (lane == 0) part[wave] = a;
        __syncthreads();
        if (t == 0)
            out[0] = (part[0] + part[1] + part[2] + part[3])
                     * (1.0f / (float)BDIM);
    }
}

// ---------------------------------------------------------------------------
extern "C" void kernel_launch(void* const* d_in, const int* in_sizes, int n_in,
                              void* d_out, int out_size, void* d_ws, size_t ws_size,
                              hipStream_t stream)
{
    const float* z1 = (const float*)d_in[0];
    const float* z2 = (const float*)d_in[1];
    float* out = (float*)d_out;

    char* ws = (char*)d_ws;
    unsigned short* A  = (unsigned short*)(ws + OFF_A);
    unsigned short* B  = (unsigned short*)(ws + OFF_B);
    float* row_sum     = (float*)(ws + OFF_RS);
    float* col_sum     = (float*)(ws + OFF_CS);
    float* diag        = (float*)(ws + OFF_DG);
    unsigned int* cnt  = (unsigned int*)(ws + OFF_CNT);

    convert_kernel<<<(BDIM * K_PAD + 255) / 256, 256, 0, stream>>>(
        z1, z2, A, B, row_sum /* rs+cs contiguous */, cnt);

    dim3 grid(BDIM / TILE, BDIM / TILE, 1);   // 64 x 64
    gemm_epilogue_kernel<<<grid, 256, 0, stream>>>(
        A, B, row_sum, col_sum, diag, cnt, out);
}

// Round 6
// 119.235 us; speedup vs baseline: 3.3670x; 3.3670x over previous
//
#include <hip/hip_runtime.h>
#include <math.h>

// ---------------------------------------------------------------------------
// HyperbolicInfoNCE on MI355X — Round 6: row-strip ownership, epilogue-hidden
// loads, no fences.
//
// R5 post-mortem: (a) compiler refused the 40-frag prefetch (VGPR capped at
// 88, serialized); (b) per-block __threadfence() = device-scope L2
// writeback/invalidate on multi-XCD -> nuked L2 residency (147->355us).
// NEVER put device-scope fences in the per-block hot path on CDNA4.
//
// R2-R5 model: ~100us of the wall is L2/L3 queuing latency paid 5x per wave
// with nothing to hide it. This round restructures ownership so the ~2300cyc
// transcendental epilogue of tile t hides the loads of tile t+1:
//   block = 128-row strip x 512-col chunk; wave = 64 rows x 4 col-tiles.
//   A-strip (20KB) stays wave-hot across 4 tiles; 64 consecutive blocks
//   share one 160KB B-chunk. Row sums accumulate in registers across tiles
//   (4x fewer row atomics); col_sum has 4 replicas to cut atomic serialization.
// ---------------------------------------------------------------------------

#define BDIM   8192
#define K_IN   129
#define K_PAD  160      // 5 * 32
#define BK     32
#define NKT    (K_PAD / BK)   // 5
#define CTILES 4              // 64-col tiles per wave

typedef __bf16  bf16x8 __attribute__((ext_vector_type(8)));
typedef float   f32x4  __attribute__((ext_vector_type(4)));

// ws layout (bytes)
#define OFF_A    0u
#define OFF_B    (BDIM * K_PAD * 2u)                  // 2,621,440
#define OFF_RS   (2u * BDIM * K_PAD * 2u)             // 5,242,880
#define OFF_CP   (OFF_RS + BDIM * 4u)                 // 4 replicas of col sums
#define OFF_DG   (OFF_CP + 4u * BDIM * 4u)

// ---- hardware transcendentals (v_sqrt_f32 / v_log_f32 / v_exp_f32) ----
__device__ __forceinline__ float fast_sqrt(float x) {
#if __has_builtin(__builtin_amdgcn_sqrtf)
    return __builtin_amdgcn_sqrtf(x);
#else
    return sqrtf(x);
#endif
}
__device__ __forceinline__ float fast_log2(float x) {
#if __has_builtin(__builtin_amdgcn_logf)
    return __builtin_amdgcn_logf(x);       // log base 2
#else
    return __log2f(x);
#endif
}
__device__ __forceinline__ float fast_exp2(float x) {
#if __has_builtin(__builtin_amdgcn_exp2f)
    return __builtin_amdgcn_exp2f(x);      // 2^x
#else
    extern "C" __device__ float __ocml_native_exp2_f32(float);
    return __ocml_native_exp2_f32(x);
#endif
}

__device__ __forceinline__ unsigned short f2bf_rne(float f) {
    unsigned int u = __float_as_uint(f);
    u += 0x7FFFu + ((u >> 16) & 1u);   // round-to-nearest-even
    return (unsigned short)(u >> 16);
}

// ---------------------------------------------------------------------------
// Kernel 1: fp32 -> bf16, K zero-padded 129->160, Lorentz metric folded into
// A (negate column 0 of z1). Also zeroes row_sum + 4 col_sum replicas
// (contiguous, 5*BDIM floats). diag is fully overwritten -> no zeroing.
// ---------------------------------------------------------------------------
__global__ __launch_bounds__(256) void convert_kernel(
    const float* __restrict__ z1, const float* __restrict__ z2,
    unsigned short* __restrict__ A, unsigned short* __restrict__ B,
    float* __restrict__ rs_cp)
{
    int idx = blockIdx.x * 256 + threadIdx.x;
    if (idx < 5 * BDIM) rs_cp[idx] = 0.f;
    if (idx >= BDIM * K_PAD) return;
    int r = idx / K_PAD;
    int c = idx - r * K_PAD;
    float va = 0.f, vb = 0.f;
    if (c < K_IN) {
        va = z1[r * K_IN + c];
        vb = z2[r * K_IN + c];
        if (c == 0) va = -va;          // Lorentz metric on first coordinate
    }
    A[idx] = f2bf_rne(va);
    B[idx] = f2bf_rne(vb);
}

// ---------------------------------------------------------------------------
// Kernel 2: strip-GEMM with fused acosh/exp epilogue.
//   grid = 1024: bid = chunk*64 + strip  (consecutive blocks share B-chunk)
//   block: rows [strip*128, +128) x cols [chunk*512, +512), 4 waves 2x2,
//   wave: 64 rows x 256 cols = 4 col-tiles of 64x64 (4x4 MFMA 16x16x32 each)
//   fragment layouts (guide-verified, m89/m91):
//     A/B: elem [m=lane&15][k=(lane>>4)*8 + j]
//     C/D: elem [row=(lane>>4)*4 + reg][col=lane&15]
// ---------------------------------------------------------------------------
__global__ __launch_bounds__(256, 2) void gemm_epilogue_kernel(
    const unsigned short* __restrict__ A, const unsigned short* __restrict__ B,
    float* __restrict__ row_sum, float* __restrict__ col_part,
    float* __restrict__ diag)
{
    const int t    = threadIdx.x;
    const int lane = t & 63;
    const int wave = t >> 6;
    const int quad = lane >> 4;
    const int l16  = lane & 15;

    const int strip = blockIdx.x & 63;
    const int chunk = blockIdx.x >> 6;
    const int wr      = (wave >> 1) * 64;           // wave row offset in strip
    const int rowBase = strip * 128 + wr;           // wave's first row
    const int colWave = chunk * 512 + (wave & 1) * 256;  // wave's first col

    const unsigned short* Abase = A + (rowBase + l16) * K_PAD + quad * 8;
    float* colRep = col_part + (strip & 3) * BDIM;  // contention / 4

    float rowp[4][4] = {};   // persistent across col-tiles

    for (int ct = 0; ct < CTILES; ++ct) {
        const int colBase = colWave + ct * 64;
        const unsigned short* Bbase = B + (colBase + l16) * K_PAD + quad * 8;

        f32x4 acc[4][4] = {};
        #pragma unroll
        for (int kt = 0; kt < NKT; ++kt) {
            bf16x8 af[4], bfr[4];
            #pragma unroll
            for (int i = 0; i < 4; ++i) {
                af[i]  = *(const bf16x8*)(Abase + i * 16 * K_PAD + kt * BK);
                bfr[i] = *(const bf16x8*)(Bbase + i * 16 * K_PAD + kt * BK);
            }
            #pragma unroll
            for (int i = 0; i < 4; ++i)
                #pragma unroll
                for (int j = 0; j < 4; ++j)
                    acc[i][j] = __builtin_amdgcn_mfma_f32_16x16x32_bf16(
                                    af[i], bfr[j], acc[i][j], 0, 0, 0);
        }

        // ---- fused epilogue for this 64x64 tile ----
        // u = x + sqrt(x^2-1), x = max(-inner, 1+1e-6)
        // exp(sims) = exp2(-14.2857142857 * log2(u))
        // sims      = -(ln2/0.07) * log2(u)
        const bool diagTile = (colBase == rowBase);
        float colp[4] = {0.f, 0.f, 0.f, 0.f};

        #pragma unroll
        for (int i = 0; i < 4; ++i) {
            #pragma unroll
            for (int j = 0; j < 4; ++j) {
                #pragma unroll
                for (int reg = 0; reg < 4; ++reg) {
                    float inner = acc[i][j][reg];
                    float x = fmaxf(-inner, 1.000001f);
                    float s = fast_sqrt(__builtin_fmaf(x, x, -1.0f));
                    float l2u = fast_log2(x + s);
                    float e = fast_exp2(-14.285714285714286f * l2u);
                    rowp[i][reg] += e;
                    colp[j]      += e;
                    if (diagTile && i == j && (quad * 4 + reg) == l16) {
                        int R = rowBase + i * 16 + quad * 4 + reg;
                        diag[R] = -9.902102579427789f * l2u;
                    }
                }
            }
        }

        // col sums for this tile: reduce across quads, one atomic per col
        #pragma unroll
        for (int j = 0; j < 4; ++j) {
            float v = colp[j];
            v += __shfl_xor(v, 16);
            v += __shfl_xor(v, 32);
            if (quad == 0)
                atomicAdd(&colRep[colBase + j * 16 + l16], v);
        }
    }

    // row sums: accumulated over all 4 col-tiles; reduce across the 16 lanes
    // of each quad (they hold the cols), one atomic per row
    #pragma unroll
    for (int i = 0; i < 4; ++i) {
        #pragma unroll
        for (int reg = 0; reg < 4; ++reg) {
            float v = rowp[i][reg];
            v += __shfl_xor(v, 1);
            v += __shfl_xor(v, 2);
            v += __shfl_xor(v, 4);
            v += __shfl_xor(v, 8);
            if (l16 == 0)
                atomicAdd(&row_sum[rowBase + i * 16 + quad * 4 + reg], v);
        }
    }
}

// ---------------------------------------------------------------------------
// Kernel 3: loss = mean_b( 0.5*(ln rs[b] + ln cs[b]) - diag[b] ),
// cs[b] = sum of 4 replicas.
// ---------------------------------------------------------------------------
__global__ __launch_bounds__(1024) void finalize_kernel(
    const float* __restrict__ rs, const float* __restrict__ cp,
    const float* __restrict__ dg, float* __restrict__ out)
{
    __shared__ float part[16];
    int t = threadIdx.x;
    float a = 0.f;
    const float LN2_HALF = 0.34657359027997264f;  // 0.5 * ln2
    for (int b = t; b < BDIM; b += 1024) {
        float cs = cp[b] + cp[b + BDIM] + cp[b + 2 * BDIM] + cp[b + 3 * BDIM];
        a += LN2_HALF * (fast_log2(rs[b]) + fast_log2(cs)) - dg[b];
    }
    #pragma unroll
    for (int m = 1; m < 64; m <<= 1) a += __shfl_xor(a, m);
    if ((t & 63) == 0) part[t >> 6] = a;
    __syncthreads();
    if (t < 16) {
        float v = part[t];
        #pragma unroll
        for (int m = 1; m < 16; m <<= 1) v += __shfl_xor(v, m);
        if (t == 0) out[0] = v * (1.0f / (float)BDIM);
    }
}

// ---------------------------------------------------------------------------
extern "C" void kernel_launch(void* const* d_in, const int* in_sizes, int n_in,
                              void* d_out, int out_size, void* d_ws, size_t ws_size,
                              hipStream_t stream)
{
    const float* z1 = (const float*)d_in[0];
    const float* z2 = (const float*)d_in[1];
    float* out = (float*)d_out;

    char* ws = (char*)d_ws;
    unsigned short* A  = (unsigned short*)(ws + OFF_A);
    unsigned short* B  = (unsigned short*)(ws + OFF_B);
    float* row_sum     = (float*)(ws + OFF_RS);
    float* col_part    = (float*)(ws + OFF_CP);
    float* diag        = (float*)(ws + OFF_DG);

    convert_kernel<<<(BDIM * K_PAD + 255) / 256, 256, 0, stream>>>(
        z1, z2, A, B, row_sum /* rs + 4 col replicas contiguous */);

    gemm_epilogue_kernel<<<1024, 256, 0, stream>>>(
        A, B, row_sum, col_part, diag);

    finalize_kernel<<<1, 1024, 0, stream>>>(row_sum, col_part, diag, out);
}